// Round 2
// baseline (271.377 us; speedup 1.0000x reference)
//
#include <hip/hip_runtime.h>
#include <stdint.h>

// LinearAttend: q,k,v (4,8,64,8192) fp32.
//   out[j][s] = sum_i (C'[i][j]/rowsum[i]) * 0.125 * exp(q[i][s])/colsum[s]
//   C'[i][j]  = sum_s exp(k[i][s]) * v[j][s]
// Split-bf16 MFMA (x = hi + lo, 3 MFMAs), error ~2^-18 relative.
//
// ctx v3: barrier-free, LDS-free, direct global->register fragments.
// v2 post-mortem: the 2-phase LDS schedule capped outstanding loads at ~4
// per wave with long vmcnt+barrier drains between (avg in-flight ~2-4
// loads/CU -> 1.35 TB/s). v3: each wave owns a 2x2 tile block, loads its
// A/B fragments straight from global (contiguous 32 B/lane), software-
// pipelined one K-step ahead, no syncs at all. 2x wave redundancy on K and
// V rows is absorbed by the XCD-local L2. 1024 blocks x 4 waves, no LDS.

typedef __attribute__((ext_vector_type(8))) short bf16x8;
typedef __attribute__((ext_vector_type(4))) float floatx4;

constexpr int D = 64, S = 8192, HEADS = 32;
constexpr int NC = 32;               // ctx chunks per head
constexpr int CHUNK = S / NC;        // 256 s per ctx block
constexpr int NK = CHUNK / 32;       // 8 K-steps of 32 cols

__device__ __forceinline__ short bf16_rn(float x) {
    unsigned u = __builtin_bit_cast(unsigned, x);
    return (short)((u + 0x8000u) >> 16);
}
__device__ __forceinline__ float bf16_f(short h) {
    unsigned u = ((unsigned)(unsigned short)h) << 16;
    return __builtin_bit_cast(float, u);
}
__device__ __forceinline__ void split8(const float* x, bf16x8& hi, bf16x8& lo) {
#pragma unroll
    for (int e = 0; e < 8; ++e) {
        short h = bf16_rn(x[e]);
        hi[e] = h;
        lo[e] = bf16_rn(x[e] - bf16_f(h));
    }
}

// ---------------------------------------------------------------- ctx ----
// Grid (32 heads, 32 chunks) x 256 (4 waves). Wave (wr,wc)=(w>>1,w&1) owns
// output tiles mt in {2wr,2wr+1}, nt in {2wc,2wc+1}. Per K-step a lane
// loads 2 A-fragments (K rows) + 2 B-fragments (V rows), 8 contiguous
// floats each; exp+split A, split B, 12 MFMAs. Double-buffered raw
// registers so next step's 8 dwordx4 loads fly under current compute.
__global__ __launch_bounds__(256, 3) void ctx_kernel(
    const float* __restrict__ K, const float* __restrict__ V,
    float* __restrict__ Cpart,   // [h][c][tile][reg][lane]
    float* __restrict__ Rpart)   // [h][c][64] rowsums
{
    const int h = blockIdx.x, c = blockIdx.y;
    const int wave = threadIdx.x >> 6, lane = threadIdx.x & 63;
    const int m = lane & 15, quad = lane >> 4;
    const int wr = wave >> 1, wc = wave & 1;

    const float* Kb = K + (size_t)h * D * S + (c * CHUNK + quad * 8);
    const float* Vb = V + (size_t)h * D * S + (c * CHUNK + quad * 8);

    const float* pa[2];
    const float* pb[2];
#pragma unroll
    for (int x = 0; x < 2; ++x) {
        pa[x] = Kb + (size_t)((wr * 2 + x) * 16 + m) * S;
        pb[x] = Vb + (size_t)((wc * 2 + x) * 16 + m) * S;
    }

    floatx4 acc[2][2];
#pragma unroll
    for (int a = 0; a < 2; ++a)
#pragma unroll
        for (int b = 0; b < 2; ++b) acc[a][b] = (floatx4){0.f, 0.f, 0.f, 0.f};
    float rs[2] = {0.f, 0.f};

    float ka0[2][8], va0[2][8], ka1[2][8], va1[2][8];

    auto loadstep = [&](float (*ka)[8], float (*va)[8], int kk) {
        const int off = kk * 32;
#pragma unroll
        for (int x = 0; x < 2; ++x) {
            *(float4*)&ka[x][0] = *(const float4*)(pa[x] + off);
            *(float4*)&ka[x][4] = *(const float4*)(pa[x] + off + 4);
            *(float4*)&va[x][0] = *(const float4*)(pb[x] + off);
            *(float4*)&va[x][4] = *(const float4*)(pb[x] + off + 4);
        }
    };

    auto compute = [&](float (*ka)[8], float (*va)[8]) {
        bf16x8 ah[2], al[2], bh[2], bl[2];
#pragma unroll
        for (int x = 0; x < 2; ++x) {
            float ex[8];
#pragma unroll
            for (int e = 0; e < 8; ++e) {
                ex[e] = __expf(ka[x][e]);
                rs[x] += ex[e];
            }
            split8(ex, ah[x], al[x]);
            split8(va[x], bh[x], bl[x]);
        }
#pragma unroll
        for (int a = 0; a < 2; ++a)
#pragma unroll
            for (int b = 0; b < 2; ++b) {
                acc[a][b] = __builtin_amdgcn_mfma_f32_16x16x32_bf16(
                    ah[a], bh[b], acc[a][b], 0, 0, 0);
                acc[a][b] = __builtin_amdgcn_mfma_f32_16x16x32_bf16(
                    ah[a], bl[b], acc[a][b], 0, 0, 0);
                acc[a][b] = __builtin_amdgcn_mfma_f32_16x16x32_bf16(
                    al[a], bh[b], acc[a][b], 0, 0, 0);
            }
    };

    loadstep(ka0, va0, 0);
#pragma unroll
    for (int kk = 0; kk < NK; kk += 2) {
        if (kk + 1 < NK) loadstep(ka1, va1, kk + 1);
        compute(ka0, va0);
        if (kk + 2 < NK) loadstep(ka0, va0, kk + 2);
        compute(ka1, va1);
    }

    // rowsum: butterfly over quad bits -> row totals at all lanes
#pragma unroll
    for (int x = 0; x < 2; ++x) {
        float v0 = rs[x];
        v0 += __shfl_xor(v0, 16, 64);
        v0 += __shfl_xor(v0, 32, 64);
        rs[x] = v0;
    }

    const size_t pbase = ((size_t)(h * NC + c)) << 12;
#pragma unroll
    for (int a = 0; a < 2; ++a)
#pragma unroll
        for (int b = 0; b < 2; ++b) {
            const int tile = (wr * 2 + a) * 4 + (wc * 2 + b);
#pragma unroll
            for (int r = 0; r < 4; ++r)
                Cpart[pbase + ((size_t)(tile * 4 + r) << 6) + lane] = acc[a][b][r];
        }
    if (wc == 0 && lane < 16) {
#pragma unroll
        for (int x = 0; x < 2; ++x)
            Rpart[(((size_t)(h * NC + c)) << 6) + (wr * 2 + x) * 16 + lane] = rs[x];
    }
}

// ------------------------------------------------------------- reduce ----
// Grid (32 heads, 8 parts) x 256. Element (tile,reg,lane):
// i = mt*16 + (lane>>4)*4 + reg, j = nt*16 + (lane&15).
// Write CnT[j][i] = sum * 0.125 / rowsum[i].
__global__ __launch_bounds__(256) void reduce_kernel(
    const float* __restrict__ Cpart, const float* __restrict__ Rpart,
    float* __restrict__ CnT)
{
    __shared__ float invr[D];
    const int h = blockIdx.x, p = blockIdx.y, t = threadIdx.x;

    if (t < D) {
        float s = 0.f;
#pragma unroll
        for (int c = 0; c < NC; ++c)
            s += Rpart[(((size_t)(h * NC + c)) << 6) + t];
        invr[t] = 0.125f / s;
    }
    __syncthreads();

#pragma unroll
    for (int k = 0; k < 2; ++k) {
        const int idx = (p << 9) + (k << 8) + t;
        float s = 0.f;
#pragma unroll
        for (int c = 0; c < NC; ++c)
            s += Cpart[(((size_t)(h * NC + c)) << 12) + idx];
        const int tile = idx >> 8, reg = (idx >> 6) & 3, lane = idx & 63;
        const int mtl = tile >> 2, ntl = tile & 3;
        const int i = mtl * 16 + ((lane >> 4) << 2) + reg;
        const int j = ntl * 16 + (lane & 15);
        CnT[((size_t)h << 12) + j * 64 + i] = s * invr[i];
    }
}

// ---------------------------------------------------------------- out ----
// Grid (32 heads, 16) x 256. Wave covers 128 s (8 iters of 16 s).
// A = CnT rows (preloaded/split once), B = exp(q) columns; colsum via
// quad butterfly; divide at epilogue. No LDS. (Unchanged this round.)
__global__ __launch_bounds__(256) void out_kernel(
    const float* __restrict__ Q, const float* __restrict__ CnT,
    float* __restrict__ Out)
{
    const int h = blockIdx.x;
    const int wave = threadIdx.x >> 6, lane = threadIdx.x & 63;
    const int m = lane & 15, quad = lane >> 4;
    const int sbase = (blockIdx.y * 4 + wave) * 128;

    bf16x8 Ah[4][2], Al[4][2];
    const float* Cb = CnT + (size_t)h * 4096;
#pragma unroll
    for (int jt = 0; jt < 4; ++jt)
#pragma unroll
        for (int kk = 0; kk < 2; ++kk) {
            float a[8];
            const float* p = Cb + (jt * 16 + m) * 64 + kk * 32 + quad * 8;
            *(float4*)&a[0] = *(const float4*)p;
            *(float4*)&a[4] = *(const float4*)(p + 4);
            split8(a, Ah[jt][kk], Al[jt][kk]);
        }

    const float* Qb = Q + (size_t)h * D * S;
    float* Ob = Out + (size_t)h * D * S;

    for (int it = 0; it < 8; ++it) {
        const int scol = sbase + it * 16 + m;
        float e[16];
        float cs = 0.f;
#pragma unroll
        for (int kk = 0; kk < 2; ++kk)
#pragma unroll
            for (int j2 = 0; j2 < 8; ++j2) {
                const float qv = Qb[(size_t)(kk * 32 + quad * 8 + j2) * S + scol];
                const float ev = __expf(qv);
                e[kk * 8 + j2] = ev;
                cs += ev;
            }
        cs += __shfl_xor(cs, 16, 64);
        cs += __shfl_xor(cs, 32, 64);
        const float inv = 1.0f / cs;

        bf16x8 Bh[2], Bl[2];
        split8(&e[0], Bh[0], Bl[0]);
        split8(&e[8], Bh[1], Bl[1]);

#pragma unroll
        for (int jt = 0; jt < 4; ++jt) {
            floatx4 a = (floatx4){0.f, 0.f, 0.f, 0.f};
#pragma unroll
            for (int kk = 0; kk < 2; ++kk) {
                a = __builtin_amdgcn_mfma_f32_16x16x32_bf16(Ah[jt][kk], Bh[kk], a, 0, 0, 0);
                a = __builtin_amdgcn_mfma_f32_16x16x32_bf16(Ah[jt][kk], Bl[kk], a, 0, 0, 0);
                a = __builtin_amdgcn_mfma_f32_16x16x32_bf16(Al[jt][kk], Bh[kk], a, 0, 0, 0);
            }
#pragma unroll
            for (int r = 0; r < 4; ++r)
                Ob[(size_t)(jt * 16 + quad * 4 + r) * S + scol] = a[r] * inv;
        }
    }
}

extern "C" void kernel_launch(void* const* d_in, const int* in_sizes, int n_in,
                              void* d_out, int out_size, void* d_ws, size_t ws_size,
                              hipStream_t stream) {
    const float* q = (const float*)d_in[0];
    const float* k = (const float*)d_in[1];
    const float* v = (const float*)d_in[2];
    float* out = (float*)d_out;

    float* Cpart = (float*)d_ws;                           // 32*32*4096*4 = 16.78 MB
    float* Rpart = Cpart + (size_t)HEADS * NC * 4096;      // 256 KB
    float* CnT   = Rpart + (size_t)HEADS * NC * 64;        // 512 KB

    ctx_kernel<<<dim3(HEADS, NC), 256, 0, stream>>>(k, v, Cpart, Rpart);
    reduce_kernel<<<dim3(HEADS, 8), 256, 0, stream>>>(Cpart, Rpart, CnT);
    out_kernel<<<dim3(HEADS, 16), 256, 0, stream>>>(q, CnT, out);
}